// Round 5
// baseline (223.138 us; speedup 1.0000x reference)
//
#include <hip/hip_runtime.h>

// HierarchicalClassifier: B=16384, D=2048, N_TOP=8, N_CLASS=16
// out[b, t*16+c] = sigmoid(f.top_W[t]+top_b[t]) * softmax_c(f.bottom_W[t,:,c]+bot_b[t,c])
//
// R11: traffic restructure. R7/R9/R10 (3 different schedule-forcing devices)
// all landed at the same ~70-78us -> scheduling was never binding; B TRAFFIC is.
// B bytes = (16384/rows_per_block)*576KB: M_ROWS=16 -> 590MB, which at the
// observed ~9.2TB/s effective L2/L3 service rate IS the 78us (A's 134MB stream
// continuously evicts B from the 4MB/XCD L2 -> B re-reads hit L3). R6 (rows=32,
// 295MB) being faster at LOWER occupancy confirms.
// Fix: rows=64/block, NO K-split. 4 waves x 16 rows, full K (64 steps of K32).
// B staged ONCE per block into LDS (global_load_lds w=16), shared by all 4
// waves -> B traffic 147MB. Triple-buffered LDS (write slot s+2 never races
// reads of slot s with one barrier/step), counted VWAIT(5) + RAW s_barrier
// (no vmcnt0 drain - m201-verified semantics), A pinned via asm GL4.
// acc=36 VGPR/wave, no cross-wave reduction; epilogue per-wave.

#define D_DIM 2048
#define NTILE 9            // 144 columns / 16
#define M_ROWS 64          // rows per block (16 per wave)
#define STEP_HALFS 6144    // B step stride: 12KB (9KB used + pad to 3*256*16B)
#define NSTEPS 64          // K steps of 32

using f32x4 = float __attribute__((ext_vector_type(4)));
using half8 = _Float16 __attribute__((ext_vector_type(8)));
using fp16x2 = __fp16 __attribute__((ext_vector_type(2)));

// B layout: S[KS*6144 + (nt*64 + lane)*8 + j]
//   = W[n = nt*16 + (lane&15)][k = KS*32 + (lane>>4)*8 + j],  KS in [0,64)
// W rows 0..7 = top_W, 8..135 = bottom_W[t][:,c] (n-8 = t*16+c), 136..143 = 0.
// Bytes [9216,12288) of each step are pad (staged but never read).
__global__ void prep_weights(const float* __restrict__ topW,
                             const float* __restrict__ botW,
                             _Float16* __restrict__ S) {
    int idx = blockIdx.x * blockDim.x + threadIdx.x;   // [0, 64*9*64)
    if (idx >= NSTEPS * NTILE * 64) return;
    int lane = idx & 63;
    int tmp  = idx >> 6;          // KS*9 + nt
    int nt   = tmp % NTILE;
    int KS   = tmp / NTILE;       // [0,64)
    int n     = nt * 16 + (lane & 15);
    int kbase = KS * 32 + (lane >> 4) * 8;

    _Float16 v[8];
    #pragma unroll
    for (int j = 0; j < 8; j++) {
        int k = kbase + j;
        float x = 0.0f;
        if (n < 8) {
            x = topW[n * D_DIM + k];
        } else if (n < 136) {
            int t = (n - 8) >> 4, c = (n - 8) & 15;
            x = botW[(t * D_DIM + k) * 16 + c];
        }
        v[j] = (_Float16)x;
    }
    *(half8*)(S + (size_t)KS * STEP_HALFS + (size_t)(nt * 64 + lane) * 8) = *(half8*)v;
}

static __device__ __forceinline__ half8 pack_af(f32x4 a, f32x4 b) {
    fp16x2 p0 = __builtin_amdgcn_cvt_pkrtz(a[0], a[1]);
    fp16x2 p1 = __builtin_amdgcn_cvt_pkrtz(a[2], a[3]);
    fp16x2 p2 = __builtin_amdgcn_cvt_pkrtz(b[0], b[1]);
    fp16x2 p3 = __builtin_amdgcn_cvt_pkrtz(b[2], b[3]);
    half8 r;
    r[0] = (_Float16)p0[0]; r[1] = (_Float16)p0[1];
    r[2] = (_Float16)p1[0]; r[3] = (_Float16)p1[1];
    r[4] = (_Float16)p2[0]; r[5] = (_Float16)p2[1];
    r[6] = (_Float16)p3[0]; r[7] = (_Float16)p3[1];
    return r;
}

// Pinned global load: saddr (SGPR pair) + 32-bit voffset + 13-bit signed imm.
#define GL4(dst, voff, sbase, IMM)                                         \
    asm volatile("global_load_dwordx4 %0, %1, %2 offset:%3"                \
                 : "=v"(dst) : "v"(voff), "s"(sbase), "i"(IMM))

#define VWAIT(N) do {                                                      \
        asm volatile("s_waitcnt vmcnt(%0)" :: "i"(N) : "memory");          \
        __builtin_amdgcn_sched_barrier(0);                                 \
    } while (0)

#define SB() __builtin_amdgcn_sched_barrier(0)
#define BAR() do { __builtin_amdgcn_s_barrier();                           \
                   __builtin_amdgcn_sched_barrier(0); } while (0)

typedef __attribute__((address_space(1))) const void gv_t;
typedef __attribute__((address_space(3))) void lv_t;

__global__ __launch_bounds__(256, 2) void hc_fused(
        const float* __restrict__ feat, const _Float16* __restrict__ Bsw,
        const float* __restrict__ top_b, const float* __restrict__ bot_b,
        float* __restrict__ out) {
    __shared__ _Float16 bufB[3][STEP_HALFS];   // 36 KB triple buffer
    __shared__ float red[4][16][148];          // 37.9 KB epilogue scratch

    const int tid  = threadIdx.x;
    const int lane = tid & 63, wave = tid >> 6;
    const int quad = lane >> 4, low = lane & 15;
    const int rowg0 = blockIdx.x * M_ROWS + wave * 16;   // this wave's 16 rows

    const unsigned long long sA = (unsigned long long)feat;
    // A: lane (low,quad) reads feat[rowg0+low][quad*8 + s*32 + {0..7}]
    const unsigned aBase = (unsigned)(((unsigned)(rowg0 + low) * D_DIM + quad * 8) * 4);

    f32x4 acc[NTILE];
    #pragma unroll
    for (int i = 0; i < NTILE; i++) acc[i] = (f32x4)0.0f;

    f32x4 aX0, aX1, aY0, aY1;   // A double-buffer (even/odd step), pinned asm

    // Cooperative B stage: 12KB -> bufB[slot], 3 x global_load_lds(16B)/thread.
    // LDS dest per wave-instr: uniform base + lane*16 (linear layout matches).
#define STAGE(GSRC, SLOT) do {                                             \
        const _Float16* g_ = (GSRC) + (size_t)tid * 8;                     \
        _Pragma("unroll")                                                  \
        for (int r_ = 0; r_ < 3; r_++) {                                   \
            __builtin_amdgcn_global_load_lds(                              \
                (gv_t*)(g_ + r_ * 2048),                                   \
                (lv_t*)&bufB[SLOT][(unsigned)(r_ * 256 + wave * 64) * 8],  \
                16, 0, 0);                                                 \
        }                                                                  \
    } while (0)

#define COMPUTE(SLOT, AL0, AL1) do {                                       \
        const _Float16* Lp_ = &bufB[SLOT][(unsigned)lane * 8];             \
        half8 f0_ = *(const half8*)(Lp_);                                  \
        half8 f1_ = *(const half8*)(Lp_ +  512);                           \
        half8 f2_ = *(const half8*)(Lp_ + 1024);                           \
        half8 f3_ = *(const half8*)(Lp_ + 1536);                           \
        half8 f4_ = *(const half8*)(Lp_ + 2048);                           \
        half8 f5_ = *(const half8*)(Lp_ + 2560);                           \
        half8 f6_ = *(const half8*)(Lp_ + 3072);                           \
        half8 f7_ = *(const half8*)(Lp_ + 3584);                           \
        half8 f8_ = *(const half8*)(Lp_ + 4096);                           \
        const half8 af_ = pack_af(AL0, AL1);                               \
        acc[0] = __builtin_amdgcn_mfma_f32_16x16x32_f16(af_, f0_, acc[0], 0, 0, 0); \
        acc[1] = __builtin_amdgcn_mfma_f32_16x16x32_f16(af_, f1_, acc[1], 0, 0, 0); \
        acc[2] = __builtin_amdgcn_mfma_f32_16x16x32_f16(af_, f2_, acc[2], 0, 0, 0); \
        acc[3] = __builtin_amdgcn_mfma_f32_16x16x32_f16(af_, f3_, acc[3], 0, 0, 0); \
        acc[4] = __builtin_amdgcn_mfma_f32_16x16x32_f16(af_, f4_, acc[4], 0, 0, 0); \
        acc[5] = __builtin_amdgcn_mfma_f32_16x16x32_f16(af_, f5_, acc[5], 0, 0, 0); \
        acc[6] = __builtin_amdgcn_mfma_f32_16x16x32_f16(af_, f6_, acc[6], 0, 0, 0); \
        acc[7] = __builtin_amdgcn_mfma_f32_16x16x32_f16(af_, f7_, acc[7], 0, 0, 0); \
        acc[8] = __builtin_amdgcn_mfma_f32_16x16x32_f16(af_, f8_, acc[8], 0, 0, 0); \
    } while (0)

    // Prologue: queue (oldest->newest) = stage(0)x3, A(0)x2, stage(1)x3, A(1)x2
    STAGE(Bsw, 0); SB();
    GL4(aX0, aBase, sA, 0);   GL4(aX1, aBase, sA, 16);  SB();
    STAGE(Bsw + STEP_HALFS, 1); SB();
    GL4(aY0, aBase, sA, 128); GL4(aY1, aBase, sA, 144); SB();

    unsigned aoffX = aBase + 256;               // byte offset for A(s+2), even
    unsigned aoffY = aBase + 384;               // odd
    const _Float16* gS = Bsw + (size_t)2 * STEP_HALFS;
    int se = 0, so = 1;                         // read slots of next even/odd step

    for (int i = 0; i < 31; ++i) {
        // even step s=2i: VWAIT(5) drains stage(s)+A(s), leaves stage(s+1)+A(s+1)
        VWAIT(5); BAR();
        COMPUTE(se, aX0, aX1);
        SB();
        int we = se - 1; if (we < 0) we += 3;   // (se+2)%3
        STAGE(gS, we); gS += STEP_HALFS; SB();
        GL4(aX0, aoffX, sA, 0); GL4(aX1, aoffX, sA, 16); aoffX += 256; SB();
        se = we;
        // odd step s=2i+1
        VWAIT(5); BAR();
        COMPUTE(so, aY0, aY1);
        SB();
        int wo = so - 1; if (wo < 0) wo += 3;
        STAGE(gS, wo); gS += STEP_HALFS; SB();
        GL4(aY0, aoffY, sA, 0); GL4(aY1, aoffY, sA, 16); aoffY += 256; SB();
        so = wo;
    }
    // tail: steps 62, 63 (nothing left to issue)
    VWAIT(5); BAR(); COMPUTE(se, aX0, aX1);
    VWAIT(0); BAR(); COMPUTE(so, aY0, aY1);

#undef STAGE
#undef COMPUTE

    // C/D layout (measured m89/m91): col = lane&15, row = quad*4 + reg.
    // Each wave owns the COMPLETE result for its 16 rows - no cross-wave sum.
    #pragma unroll
    for (int nt = 0; nt < NTILE; nt++) {
        #pragma unroll
        for (int r = 0; r < 4; r++) {
            red[wave][quad * 4 + r][nt * 16 + low] = acc[nt][r];
        }
    }
    __syncthreads();

    // Per-wave epilogue: lane -> (row = lane&15, tops {2*(lane>>4), +1}).
    {
        const int row = lane & 15;
        const int q2  = lane >> 4;
        #pragma unroll
        for (int tt = 0; tt < 2; tt++) {
            const int t = q2 * 2 + tt;
            float zt = red[wave][row][t] + top_b[t];
            const float sig = 1.0f / (1.0f + __expf(-zt));

            float z[16];
            float zmax = -1e30f;
            #pragma unroll
            for (int c = 0; c < 16; c++) {
                float v = red[wave][row][8 + t * 16 + c] + bot_b[t * 16 + c];
                z[c] = v;
                zmax = fmaxf(zmax, v);
            }
            float s = 0.0f;
            #pragma unroll
            for (int c = 0; c < 16; c++) { z[c] = __expf(z[c] - zmax); s += z[c]; }
            const float scale = sig / s;

            float* o = out + (size_t)(rowg0 + row) * 128 + t * 16;
            #pragma unroll
            for (int c = 0; c < 16; c += 4) {
                f32x4 v = { z[c] * scale, z[c+1] * scale, z[c+2] * scale, z[c+3] * scale };
                *(f32x4*)(o + c) = v;
            }
        }
    }
}

extern "C" void kernel_launch(void* const* d_in, const int* in_sizes, int n_in,
                              void* d_out, int out_size, void* d_ws, size_t ws_size,
                              hipStream_t stream) {
    const float* feat  = (const float*)d_in[0];   // (16384, 2048)
    const float* topW  = (const float*)d_in[1];   // (8, 2048)
    const float* topB  = (const float*)d_in[2];   // (8,)
    const float* botW  = (const float*)d_in[3];   // (8, 2048, 16)
    const float* botB  = (const float*)d_in[4];   // (8, 16)
    float* out = (float*)d_out;                   // (16384, 128)
    _Float16* Bsw = (_Float16*)d_ws;              // 64 steps * 12KB = 768 KB

    prep_weights<<<(NSTEPS * NTILE * 64 + 255) / 256, 256, 0, stream>>>(topW, botW, Bsw);
    hc_fused<<<16384 / M_ROWS, 256, 0, stream>>>(feat, Bsw, topB, botB, out);
}

// Round 6
// 215.749 us; speedup vs baseline: 1.0342x; 1.0342x over previous
//
#include <hip/hip_runtime.h>

// HierarchicalClassifier: B=16384, D=2048, N_TOP=8, N_CLASS=16
// out[b, t*16+c] = sigmoid(f.top_W[t]+top_b[t]) * softmax_c(f.bottom_W[t,:,c]+bot_b[t,c])
//
// R12: per-CU TCP-byte reduction with sane occupancy. Ledger: R7/R9/R10
// (3 schedule-forcers) and R11 (4x B-traffic cut at 1 wave/SIMD) all ~70-78us;
// R6 (2 waves/SIMD, register-B, 1.66MB/CU TCP bytes) best at ~62us. Fit:
// time ~ per-CU vector-memory bytes at ~8.5-9TB/s aggregate TCP service
// (L3-residency invariance in R8 rules out HBM). Fix = cut TCP bytes while
// holding 2 waves/SIMD: 512-thread blocks (8 waves, 1 block/CU, 2 waves/SIMD),
// M_block=64, 2-way K-split (wave = mrow*2+kg). B staged once per block per
// step into triple-buffered LDS (18KB slice = both K-halves) and re-read via
// ds_read (LDS pipe, not TCP). Per-CU TCP: B 576KB + A 512KB = 1.09MB.
// A pinned-asm GL4 3-deep (sets rotate s%3, all-literal imm: max 3984<4096),
// stage = 3 uniform global_load_lds w=16 per wave per step (3rd lane<16-
// masked: partial-exec still counts 1 vmcnt -> uniform VWAIT math).
// Counted VWAIT(7) + raw s_barrier per step (m201-verified semantics).
// LDS 128KB exactly; ~90 VGPR; epilogue kg-pair sum, 512thr = 64rows x 8tops.

#define D_DIM 2048
#define NTILE 9             // 144 columns / 16
#define M_ROWS 64           // rows per block (16 per mrow-group)
#define NSTEPS 32           // K steps of 32 per K-half (K-half = 1024)
#define STEP_BYTES 18432    // per-step slice: 2 kg-halves x 9216B, no pad
#define SLOT_HALFS 9216     // 18432B in halfs

using f32x4 = float __attribute__((ext_vector_type(4)));
using half8 = _Float16 __attribute__((ext_vector_type(8)));
using fp16x2 = __fp16 __attribute__((ext_vector_type(2)));

// B layout: S[s*9216 + kg*4608 + (nt*64+lane)*8 + j]  (halfs)
//   = W[n = nt*16 + (lane&15)][k = kg*1024 + s*32 + (lane>>4)*8 + j]
// W rows 0..7 = top_W, 8..135 = bottom_W[t][:,c] (n-8 = t*16+c), 136..143 = 0.
__global__ void prep_weights(const float* __restrict__ topW,
                             const float* __restrict__ botW,
                             _Float16* __restrict__ S) {
    int idx = blockIdx.x * blockDim.x + threadIdx.x;   // [0, 32*2*9*64)
    if (idx >= NSTEPS * 2 * NTILE * 64) return;
    int lane = idx & 63;
    int tmp  = idx >> 6;          // skg*9 + nt
    int nt   = tmp % NTILE;
    int skg  = tmp / NTILE;       // s*2 + kg in [0,64)
    int kg   = skg & 1;
    int s    = skg >> 1;
    int n     = nt * 16 + (lane & 15);
    int kbase = kg * 1024 + s * 32 + (lane >> 4) * 8;

    _Float16 v[8];
    #pragma unroll
    for (int j = 0; j < 8; j++) {
        int k = kbase + j;
        float x = 0.0f;
        if (n < 8) {
            x = topW[n * D_DIM + k];
        } else if (n < 136) {
            int t = (n - 8) >> 4, c = (n - 8) & 15;
            x = botW[(t * D_DIM + k) * 16 + c];
        }
        v[j] = (_Float16)x;
    }
    *(half8*)(S + (size_t)s * SLOT_HALFS + (size_t)kg * 4608
                + (size_t)(nt * 64 + lane) * 8) = *(half8*)v;
}

static __device__ __forceinline__ half8 pack_af(f32x4 a, f32x4 b) {
    fp16x2 p0 = __builtin_amdgcn_cvt_pkrtz(a[0], a[1]);
    fp16x2 p1 = __builtin_amdgcn_cvt_pkrtz(a[2], a[3]);
    fp16x2 p2 = __builtin_amdgcn_cvt_pkrtz(b[0], b[1]);
    fp16x2 p3 = __builtin_amdgcn_cvt_pkrtz(b[2], b[3]);
    half8 r;
    r[0] = (_Float16)p0[0]; r[1] = (_Float16)p0[1];
    r[2] = (_Float16)p1[0]; r[3] = (_Float16)p1[1];
    r[4] = (_Float16)p2[0]; r[5] = (_Float16)p2[1];
    r[6] = (_Float16)p3[0]; r[7] = (_Float16)p3[1];
    return r;
}

// Pinned global load: saddr (SGPR pair) + 32-bit voffset + 13-bit signed imm.
#define GL4(dst, voff, sbase, IMM)                                         \
    asm volatile("global_load_dwordx4 %0, %1, %2 offset:%3"                \
                 : "=v"(dst) : "v"(voff), "s"(sbase), "i"(IMM))

#define VWAIT(N) do {                                                      \
        asm volatile("s_waitcnt vmcnt(%0)" :: "i"(N) : "memory");          \
        __builtin_amdgcn_sched_barrier(0);                                 \
    } while (0)

#define SB() __builtin_amdgcn_sched_barrier(0)
#define BAR() do { __builtin_amdgcn_s_barrier();                           \
                   __builtin_amdgcn_sched_barrier(0); } while (0)

typedef __attribute__((address_space(1))) const void gv_t;
typedef __attribute__((address_space(3))) void lv_t;

__global__ __launch_bounds__(512, 1) void hc_fused(
        const float* __restrict__ feat, const _Float16* __restrict__ Bsw,
        const float* __restrict__ top_b, const float* __restrict__ bot_b,
        float* __restrict__ out) {
    __shared__ _Float16 bufB[3][SLOT_HALFS];   // 3 x 18432B = 55296B
    __shared__ float red[8][16][148];          // 75776B ; total 128KB exact

    const int tid  = threadIdx.x;
    const int lane = tid & 63, wave = tid >> 6;      // 8 waves
    const int quad = lane >> 4, low = lane & 15;
    const int mrow = wave >> 1, kg = wave & 1;       // 4 row-groups x 2 K-halves
    const int rowg0 = blockIdx.x * M_ROWS + mrow * 16;

    const unsigned long long sA = (unsigned long long)feat;
    // A: lane (low,quad) reads feat[rowg0+low][kg*1024 + s*32 + quad*8 + {0..7}]
    // step offset = s*128B, all-literal imm (max 31*128+16 = 3984 < 4096).
    const unsigned vA = (unsigned)(((unsigned)(rowg0 + low) * D_DIM
                                    + kg * 1024 + quad * 8) * 4);

    const char* gB = (const char*)Bsw;         // step s slice at s*18432
    const char* lB = (const char*)&bufB[0][0];

    f32x4 acc[NTILE];
    #pragma unroll
    for (int i = 0; i < NTILE; i++) acc[i] = (f32x4)0.0f;

    // A register sets rotate with period 3: step s uses set s%3, and during
    // step s set s%3 is reloaded with A(s+3).
    f32x4 aX0, aX1, aY0, aY1, aZ0, aZ1;

    // Cooperative stage of step KS into slot: 18432B, wave w owns bytes
    // [w*2304, (w+1)*2304): 2 full 16B wave-instrs + one lane<16 instr.
    // Uniform 3 vmcnt-increments per wave per stage.
#define STAGE(SLOT, KS) do {                                               \
        const char* g0_ = gB + (KS) * STEP_BYTES + wave * 2304             \
                             + (unsigned)lane * 16;                        \
        const char* l0_ = lB + (SLOT) * STEP_BYTES + wave * 2304;          \
        __builtin_amdgcn_global_load_lds((gv_t*)(g0_),                     \
                                         (lv_t*)(l0_), 16, 0, 0);          \
        __builtin_amdgcn_global_load_lds((gv_t*)(g0_ + 1024),              \
                                         (lv_t*)(l0_ + 1024), 16, 0, 0);   \
        if (low16_) {                                                      \
            __builtin_amdgcn_global_load_lds((gv_t*)(g0_ + 2048),          \
                                             (lv_t*)(l0_ + 2048), 16, 0, 0);\
        }                                                                  \
    } while (0)
    const bool low16_ = (lane < 16);

    // B fragments for this wave's kg-half: bufB[slot] + kg*9216B + (nt*64+lane)*16B
    const _Float16* Lb = (const _Float16*)lB + kg * 4608 + lane * 8;

#define COMPUTE(KS, A0r, A1r) do {                                         \
        const _Float16* Lp_ = Lb + ((KS) % 3) * SLOT_HALFS;                \
        half8 f0_ = *(const half8*)(Lp_);                                  \
        half8 f1_ = *(const half8*)(Lp_ +  512);                           \
        half8 f2_ = *(const half8*)(Lp_ + 1024);                           \
        half8 f3_ = *(const half8*)(Lp_ + 1536);                           \
        half8 f4_ = *(const half8*)(Lp_ + 2048);                           \
        half8 f5_ = *(const half8*)(Lp_ + 2560);                           \
        half8 f6_ = *(const half8*)(Lp_ + 3072);                           \
        half8 f7_ = *(const half8*)(Lp_ + 3584);                           \
        half8 f8_ = *(const half8*)(Lp_ + 4096);                           \
        const half8 af_ = pack_af(A0r, A1r);                               \
        acc[0] = __builtin_amdgcn_mfma_f32_16x16x32_f16(af_, f0_, acc[0], 0, 0, 0); \
        acc[1] = __builtin_amdgcn_mfma_f32_16x16x32_f16(af_, f1_, acc[1], 0, 0, 0); \
        acc[2] = __builtin_amdgcn_mfma_f32_16x16x32_f16(af_, f2_, acc[2], 0, 0, 0); \
        acc[3] = __builtin_amdgcn_mfma_f32_16x16x32_f16(af_, f3_, acc[3], 0, 0, 0); \
        acc[4] = __builtin_amdgcn_mfma_f32_16x16x32_f16(af_, f4_, acc[4], 0, 0, 0); \
        acc[5] = __builtin_amdgcn_mfma_f32_16x16x32_f16(af_, f5_, acc[5], 0, 0, 0); \
        acc[6] = __builtin_amdgcn_mfma_f32_16x16x32_f16(af_, f6_, acc[6], 0, 0, 0); \
        acc[7] = __builtin_amdgcn_mfma_f32_16x16x32_f16(af_, f7_, acc[7], 0, 0, 0); \
        acc[8] = __builtin_amdgcn_mfma_f32_16x16x32_f16(af_, f8_, acc[8], 0, 0, 0); \
    } while (0)

    // Step KS: wait W, barrier, compute from slot KS%3 + A-set KS%3,
    // then issue stage(KS+2) and A(KS+3) (guards compile-time folded).
#define STEP(KS, W, A0r, A1r) do {                                         \
        VWAIT(W); BAR();                                                   \
        COMPUTE(KS, A0r, A1r); SB();                                       \
        if ((KS) + 2 < NSTEPS) { STAGE(((KS) + 2) % 3, (KS) + 2); } SB();  \
        if ((KS) + 3 < NSTEPS) {                                           \
            GL4(A0r, vA, sA, ((KS) + 3) * 128);                            \
            GL4(A1r, vA, sA, ((KS) + 3) * 128 + 16);                       \
        } SB();                                                            \
    } while (0)

    // Prologue queue (oldest->newest): stage0(3), A0(2), A1(2), stage1(3), A2(2)
    STAGE(0, 0); SB();
    GL4(aX0, vA, sA,   0); GL4(aX1, vA, sA,  16); SB();
    GL4(aY0, vA, sA, 128); GL4(aY1, vA, sA, 144); SB();
    STAGE(1, 1); SB();
    GL4(aZ0, vA, sA, 256); GL4(aZ1, vA, sA, 272); SB();

    // Top-of-step waits: drain stage(s)+A(s); steady leftover = 7.
    STEP( 0, 7, aX0, aX1);  STEP( 1, 7, aY0, aY1);  STEP( 2, 7, aZ0, aZ1);
    STEP( 3, 7, aX0, aX1);  STEP( 4, 7, aY0, aY1);  STEP( 5, 7, aZ0, aZ1);
    STEP( 6, 7, aX0, aX1);  STEP( 7, 7, aY0, aY1);  STEP( 8, 7, aZ0, aZ1);
    STEP( 9, 7, aX0, aX1);  STEP(10, 7, aY0, aY1);  STEP(11, 7, aZ0, aZ1);
    STEP(12, 7, aX0, aX1);  STEP(13, 7, aY0, aY1);  STEP(14, 7, aZ0, aZ1);
    STEP(15, 7, aX0, aX1);  STEP(16, 7, aY0, aY1);  STEP(17, 7, aZ0, aZ1);
    STEP(18, 7, aX0, aX1);  STEP(19, 7, aY0, aY1);  STEP(20, 7, aZ0, aZ1);
    STEP(21, 7, aX0, aX1);  STEP(22, 7, aY0, aY1);  STEP(23, 7, aZ0, aZ1);
    STEP(24, 7, aX0, aX1);  STEP(25, 7, aY0, aY1);  STEP(26, 7, aZ0, aZ1);
    STEP(27, 7, aX0, aX1);  STEP(28, 7, aY0, aY1);  STEP(29, 7, aZ0, aZ1);
    STEP(30, 5, aX0, aX1);  // stage(31)+A(31) still in flight after drain
    STEP(31, 0, aY0, aY1);  // drain all

#undef STEP
#undef COMPUTE
#undef STAGE

    // C/D layout (measured m89/m91): col = lane&15, row = quad*4 + reg.
    // Wave holds PARTIAL sums (its K-half) for its 16 rows.
    #pragma unroll
    for (int nt = 0; nt < NTILE; nt++) {
        #pragma unroll
        for (int r = 0; r < 4; r++) {
            red[wave][quad * 4 + r][nt * 16 + low] = acc[nt][r];
        }
    }
    __syncthreads();

    // Epilogue: 512 threads -> (row = tid>>3 in [0,64), top = tid&7).
    // Combine the kg-pair: waves mg*2 and mg*2+1 hold the two K-halves.
    {
        const int row = tid >> 3;
        const int top = tid & 7;
        const int mg  = row >> 4;
        const int r16 = row & 15;

        float zt = red[mg * 2][r16][top] + red[mg * 2 + 1][r16][top] + top_b[top];
        const float sig = 1.0f / (1.0f + __expf(-zt));

        float z[16];
        float zmax = -1e30f;
        #pragma unroll
        for (int c = 0; c < 16; c++) {
            float v = red[mg * 2][r16][8 + top * 16 + c]
                    + red[mg * 2 + 1][r16][8 + top * 16 + c]
                    + bot_b[top * 16 + c];
            z[c] = v;
            zmax = fmaxf(zmax, v);
        }
        float s = 0.0f;
        #pragma unroll
        for (int c = 0; c < 16; c++) { z[c] = __expf(z[c] - zmax); s += z[c]; }
        const float scale = sig / s;

        float* o = out + (size_t)(blockIdx.x * M_ROWS + row) * 128 + top * 16;
        #pragma unroll
        for (int c = 0; c < 16; c += 4) {
            f32x4 v = { z[c] * scale, z[c+1] * scale, z[c+2] * scale, z[c+3] * scale };
            *(f32x4*)(o + c) = v;
        }
    }
}

extern "C" void kernel_launch(void* const* d_in, const int* in_sizes, int n_in,
                              void* d_out, int out_size, void* d_ws, size_t ws_size,
                              hipStream_t stream) {
    const float* feat  = (const float*)d_in[0];   // (16384, 2048)
    const float* topW  = (const float*)d_in[1];   // (8, 2048)
    const float* topB  = (const float*)d_in[2];   // (8,)
    const float* botW  = (const float*)d_in[3];   // (8, 2048, 16)
    const float* botB  = (const float*)d_in[4];   // (8, 16)
    float* out = (float*)d_out;                   // (16384, 128)
    _Float16* Bsw = (_Float16*)d_ws;              // 32 steps * 18432B = 576 KB

    prep_weights<<<(NSTEPS * 2 * NTILE * 64 + 255) / 256, 256, 0, stream>>>(topW, botW, Bsw);
    hc_fused<<<16384 / M_ROWS, 512, 0, stream>>>(feat, Bsw, topB, botB, out);
}